// Round 5
// baseline (33.639 us; speedup 1.0000x reference)
//
#include <hip/hip_runtime.h>

#define NB 8
#define NT 1024
#define NK 8
#define NL 1024
#define NH 256
#define NE 128
#define NF 64
#define NV 23

typedef __attribute__((ext_vector_type(8))) short bf16x8;
typedef __attribute__((ext_vector_type(4))) float f32x4;

__device__ inline unsigned short f2bf(float f) {
  unsigned u = __float_as_uint(f);
  u += 0x7fffu + ((u >> 16) & 1u);
  return (unsigned short)(u >> 16);
}

__device__ inline uint4 pack8(const float4 f0, const float4 f1) {
  uint4 u;
  u.x = f2bf(f0.x) | ((unsigned)f2bf(f0.y) << 16);
  u.y = f2bf(f0.z) | ((unsigned)f2bf(f0.w) << 16);
  u.z = f2bf(f1.x) | ((unsigned)f2bf(f1.y) << 16);
  u.w = f2bf(f1.z) | ((unsigned)f2bf(f1.w) << 16);
  return u;
}

// ---------------------------------------------------------------------------
// Prep: two pre-swizzled bf16 images of W1 slices (chunk = 8 k x 1 n, 16 B).
//  imgEx (4096 chunks): g in [0,16)  -> W1 rows 256+g*8..+7   (ex slice)
//  imgB (10240 chunks): g in [0,32)  -> W1 rows g*8..+7       (hs slice)
//                       g in [32,40) -> W1 rows 384+(g-32)*8  (col slice)
//  chunk address: g*256 + (n ^ (g&7)).
//  Thread owns (g, n0..n0+3): coalesced float4 row loads, scattered 16B stores.
// ---------------------------------------------------------------------------
__global__ __launch_bounds__(64) void k_prep(const float* __restrict__ W1,
                                             uint4* __restrict__ imgEx,
                                             uint4* __restrict__ imgB) {
  const int c = blockIdx.x * 64 + threadIdx.x;  // 3584 slots of 4 chunks
  int g, n0, wrow0;
  uint4* img;
  if (c < 1024) {
    g = c >> 6; n0 = (c & 63) * 4;
    wrow0 = NH + g * 8;
    img = imgEx;
  } else {
    const int c2 = c - 1024;
    g = c2 >> 6; n0 = (c2 & 63) * 4;
    wrow0 = (g < 32) ? g * 8 : 384 + (g - 32) * 8;
    img = imgB;
  }
  float4 r[8];
#pragma unroll
  for (int j = 0; j < 8; ++j)
    r[j] = *(const float4*)&W1[(size_t)(wrow0 + j) * NH + n0];
  const float* rf = (const float*)r;  // rf[j*4 + d]
#pragma unroll
  for (int d = 0; d < 4; ++d) {
    unsigned short h[8];
#pragma unroll
    for (int j = 0; j < 8; ++j) h[j] = f2bf(rf[j * 4 + d]);
    uint4 u;
    u.x = h[0] | ((unsigned)h[1] << 16);
    u.y = h[2] | ((unsigned)h[3] << 16);
    u.z = h[4] | ((unsigned)h[5] << 16);
    u.w = h[6] | ((unsigned)h[7] << 16);
    img[g * 256 + ((n0 + d) ^ (g & 7))] = u;
  }
}

// ---------------------------------------------------------------------------
// Mega kernel: block = (b, 16 t rows), 8 waves, LDS = 64 KB (Bs) + 16 KB (Ub)
// -> 2 blocks/CU.
//   phase 1: async-stage W1ex image (64 KB) to LDS
//   phase 2: base part U[16 t][256] = hs@W1hs + col@W1col + b1 (M=16 frag,
//            B from L2-hot imgB, A direct from hs/col) -> XOR-swizzled Ub LDS
//   barrier
//   phase 3: ex MFMA, A-fragments DIRECT from global (lane-private rows,
//            f32->bf16 in-register), B from LDS. Wave w: rows w*16..+15, N=256.
//   phase 4: in-register epilogue: relu(ex+base).W2, shfl reduce, softmax(k),
//            lambda + p_copy histogram.
// ---------------------------------------------------------------------------
__global__ __launch_bounds__(512, 4) void k_mega(
    const float* __restrict__ hs, const float* __restrict__ ex,
    const float* __restrict__ col, const int* __restrict__ c_t,
    const int* __restrict__ aa_ids, const uint4* __restrict__ imgEx,
    const uint4* __restrict__ imgB, const float* __restrict__ b1,
    const float* __restrict__ W2, const float* __restrict__ b2,
    float* __restrict__ p_copy, float* __restrict__ lam) {
  extern __shared__ uint4 smem[];
  uint4* Bs = smem;          // 4096 chunks = 64 KB
  uint4* Ub = smem + 4096;   // 1024 chunks = 16 KB: row*64 + (slot ^ row)

  const int tid = threadIdx.x;
  const int lane = tid & 63;
  const int w = tid >> 6;    // 0..7
  const int lm = lane & 15;
  const int lg = lane >> 4;
  const int b = blockIdx.x >> 6;
  const int t0 = (blockIdx.x & 63) * 16;

  // ---- phase 1: async B stage (64 KB linear) ----
#pragma unroll
  for (int it = 0; it < 8; ++it) {
    const int off = (w * 8 + it) * 64;
    __builtin_amdgcn_global_load_lds(
        (const __attribute__((address_space(1))) void*)(imgEx + off + lane),
        (__attribute__((address_space(3))) void*)(Bs + off), 16, 0, 0);
  }

  // ---- phase 2: base part, M=16, global operands, result -> swizzled Ub ----
  {
    const int myt = t0 + lm;
    const int ctv = c_t[b * NT + myt];
    const int myc = ctv < 0 ? 0 : ctv;
    f32x4 accB[2];
#pragma unroll
    for (int f = 0; f < 2; ++f) {
      const float4 bv = *(const float4*)&b1[(w * 2 + f) * 16 + lg * 4];
      accB[f][0] = bv.x; accB[f][1] = bv.y; accB[f][2] = bv.z; accB[f][3] = bv.w;
    }
#pragma unroll
    for (int ks = 0; ks < 10; ++ks) {
      const int gk = ks * 4 + lg;  // 0..39
      const float* asrc = (gk < 32)
          ? &hs[((size_t)b * NT + myt) * NH + gk * 8]
          : &col[((size_t)b * NL + myc) * NF + (gk - 32) * 8];
      const float4 f0 = *(const float4*)asrc;
      const float4 f1 = *(const float4*)(asrc + 4);
      union { uint4 u; bf16x8 v; } A;
      A.u = pack8(f0, f1);
#pragma unroll
      for (int f = 0; f < 2; ++f) {
        const int n = (w * 2 + f) * 16 + lm;
        union { uint4 u; bf16x8 v; } B2;
        B2.u = imgB[(size_t)gk * 256 + (n ^ (gk & 7))];
        accB[f] = __builtin_amdgcn_mfma_f32_16x16x32_bf16(B2.v, A.v, accB[f], 0, 0, 0);
      }
    }
    // deposit: row lm, 16B-slot s = (w*2+f)*4 + lg, phys = s ^ lm
#pragma unroll
    for (int f = 0; f < 2; ++f) {
      union { uint4 u; f32x4 v; } o;
      o.v = accB[f];
      Ub[lm * 64 + (((w * 2 + f) * 4 + lg) ^ lm)] = o.u;
    }
  }

  __syncthreads();

  // ---- phase 3: ex MFMA, A direct from global ----
  // lane's row m = w*16+lm -> t_local = w*2 + (lm>>3), k = lm&7
  const int t_local = w * 2 + (lm >> 3);
  const int t = t0 + t_local;
  const int ctv = c_t[b * NT + t];
  const bool valid = ctv >= 0;
  const int c = valid ? ctv : 0;
  const float* arow = &ex[(((size_t)b * NK + (lm & 7)) * NL + c) * NE];

  f32x4 acc[16] = {};
#pragma unroll
  for (int ks = 0; ks < 4; ++ks) {
    const int g = ks * 4 + lg;
    const float4 f0 = *(const float4*)(arow + g * 8);
    const float4 f1 = *(const float4*)(arow + g * 8 + 4);
    union { uint4 u; bf16x8 v; } A;
    A.u = pack8(f0, f1);
#pragma unroll
    for (int fn = 0; fn < 16; ++fn) {
      const bf16x8 bfr = *(const bf16x8*)&Bs[g * 256 + ((fn * 16 + lm) ^ (g & 7))];
      acc[fn] = __builtin_amdgcn_mfma_f32_16x16x32_bf16(bfr, A.v, acc[fn], 0, 0, 0);
    }
  }

  // ---- phase 4: epilogue ----
  const float b2v = b2[0];
  float p = 0.f;
#pragma unroll
  for (int fn = 0; fn < 16; ++fn) {
    const int n0 = fn * 16 + lg * 4;
    union { uint4 u; f32x4 v; } ubv;
    ubv.u = Ub[t_local * 64 + ((fn * 4 + lg) ^ t_local)];
    const float4 w2v = *(const float4*)&W2[n0];
    p += fmaxf(acc[fn][0] + ubv.v[0], 0.f) * w2v.x +
         fmaxf(acc[fn][1] + ubv.v[1], 0.f) * w2v.y +
         fmaxf(acc[fn][2] + ubv.v[2], 0.f) * w2v.z +
         fmaxf(acc[fn][3] + ubv.v[3], 0.f) * w2v.w;
  }
  p += __shfl_xor(p, 16);
  p += __shfl_xor(p, 32);
  const float score = p + b2v;

  float mx = score;
  mx = fmaxf(mx, __shfl_xor(mx, 1));
  mx = fmaxf(mx, __shfl_xor(mx, 2));
  mx = fmaxf(mx, __shfl_xor(mx, 4));
  const float e = __expf(score - mx);
  float s = e;
  s += __shfl_xor(s, 1);
  s += __shfl_xor(s, 2);
  s += __shfl_xor(s, 4);
  const float wgt = valid ? (e / s) : 0.f;

  // lambda: lg==0 lanes cover 2 t rows x 8 k = 16 consecutive floats
  if (lg == 0) lam[((size_t)b * NT + t0 + w * 2) * NK + lm] = wgt;

  int aav = 0;
  if (lg == 0) aav = aa_ids[((size_t)b * NK + (lm & 7)) * NL + c];

  const int bin = lane & 31;
  const int half = lane >> 5;
  const int src0 = half * 8;  // source lanes 0..7 (row w*2) or 8..15 (row w*2+1)
  float pc = 0.f;
#pragma unroll
  for (int k = 0; k < 8; ++k) {
    const int a = __shfl(aav, src0 + k);
    const float ww = __shfl(wgt, src0 + k);
    pc += (a == bin) ? ww : 0.f;
  }
  if (bin < NV)
    p_copy[((size_t)b * NT + t0 + w * 2 + half) * NV + bin] = pc;
}

extern "C" void kernel_launch(void* const* d_in, const int* in_sizes, int n_in,
                              void* d_out, int out_size, void* d_ws, size_t ws_size,
                              hipStream_t stream) {
  const float* hs = (const float*)d_in[0];
  const float* ex = (const float*)d_in[1];
  const float* col = (const float*)d_in[2];
  const int* ct = (const int*)d_in[3];
  const int* aa = (const int*)d_in[4];
  const float* W1 = (const float*)d_in[5];
  const float* b1 = (const float*)d_in[6];
  const float* W2 = (const float*)d_in[7];
  const float* b2 = (const float*)d_in[8];

  uint4* imgEx = (uint4*)d_ws;        // 64 KB
  uint4* imgB = imgEx + 4096;         // 160 KB

  float* p_copy = (float*)d_out;
  float* lam = p_copy + (size_t)NB * NT * NV;

  const size_t lds_bytes = (4096 + 1024) * sizeof(uint4);  // 80 KB -> 2 blocks/CU

  k_prep<<<56, 64, 0, stream>>>(W1, imgEx, imgB);
  k_mega<<<NB * NT / 16, 512, lds_bytes, stream>>>(hs, ex, col, ct, aa, imgEx,
                                                   imgB, b1, W2, b2, p_copy, lam);
}

// Round 6
// 31.717 us; speedup vs baseline: 1.0606x; 1.0606x over previous
//
#include <hip/hip_runtime.h>

#define NB 8
#define NT 1024
#define NK 8
#define NL 1024
#define NH 256
#define NE 128
#define NF 64
#define NV 23

typedef __attribute__((ext_vector_type(8))) short bf16x8;
typedef __attribute__((ext_vector_type(4))) float f32x4;

__device__ inline unsigned short f2bf(float f) {
  unsigned u = __float_as_uint(f);
  u += 0x7fffu + ((u >> 16) & 1u);
  return (unsigned short)(u >> 16);
}

__device__ inline uint4 pack8(const float4 f0, const float4 f1) {
  uint4 u;
  u.x = f2bf(f0.x) | ((unsigned)f2bf(f0.y) << 16);
  u.y = f2bf(f0.z) | ((unsigned)f2bf(f0.w) << 16);
  u.z = f2bf(f1.x) | ((unsigned)f2bf(f1.y) << 16);
  u.w = f2bf(f1.z) | ((unsigned)f2bf(f1.w) << 16);
  return u;
}

// ---------------------------------------------------------------------------
// Prep: two pre-swizzled bf16 images of W1 slices (chunk = 8 k x 1 n, 16 B).
//  imgEx (4096 chunks): g in [0,16)  -> W1 rows 256+g*8..+7   (ex slice)
//  imgB (10240 chunks): g in [0,32)  -> W1 rows g*8..+7       (hs slice)
//                       g in [32,40) -> W1 rows 384+(g-32)*8  (col slice)
//  chunk address: g*256 + (n ^ (g&7)).
// ---------------------------------------------------------------------------
__global__ __launch_bounds__(64) void k_prep(const float* __restrict__ W1,
                                             uint4* __restrict__ imgEx,
                                             uint4* __restrict__ imgB) {
  const int c = blockIdx.x * 64 + threadIdx.x;  // 3584 slots of 4 chunks
  int g, n0, wrow0;
  uint4* img;
  if (c < 1024) {
    g = c >> 6; n0 = (c & 63) * 4;
    wrow0 = NH + g * 8;
    img = imgEx;
  } else {
    const int c2 = c - 1024;
    g = c2 >> 6; n0 = (c2 & 63) * 4;
    wrow0 = (g < 32) ? g * 8 : 384 + (g - 32) * 8;
    img = imgB;
  }
  float4 r[8];
#pragma unroll
  for (int j = 0; j < 8; ++j)
    r[j] = *(const float4*)&W1[(size_t)(wrow0 + j) * NH + n0];
  const float* rf = (const float*)r;  // rf[j*4 + d]
#pragma unroll
  for (int d = 0; d < 4; ++d) {
    unsigned short h[8];
#pragma unroll
    for (int j = 0; j < 8; ++j) h[j] = f2bf(rf[j * 4 + d]);
    uint4 u;
    u.x = h[0] | ((unsigned)h[1] << 16);
    u.y = h[2] | ((unsigned)h[3] << 16);
    u.z = h[4] | ((unsigned)h[5] << 16);
    u.w = h[6] | ((unsigned)h[7] << 16);
    img[g * 256 + ((n0 + d) ^ (g & 7))] = u;
  }
}

// ---------------------------------------------------------------------------
// Mega kernel: block = (b, 16 t rows), 8 waves, LDS = 64 KB (Bs) + 16 KB (Ub).
//   phase 0: PREFETCH the lane's gathered ex row (8 x float4) into registers
//   phase 1: async-stage W1ex image (64 KB) to LDS
//   phase 2: base part U[16 t][256] (M=16 frag, batched global loads) -> Ub
//   barrier
//   phase 3: ex MFMA from prefetched regs + LDS B
//   phase 4: in-register epilogue (relu.W2, shfl reduce, softmax, histogram)
// Latency hiding via ILP: launch_bounds(512,2) gives the compiler 256 VGPRs.
// ---------------------------------------------------------------------------
__global__ __launch_bounds__(512, 2) void k_mega(
    const float* __restrict__ hs, const float* __restrict__ ex,
    const float* __restrict__ col, const int* __restrict__ c_t,
    const int* __restrict__ aa_ids, const uint4* __restrict__ imgEx,
    const uint4* __restrict__ imgB, const float* __restrict__ b1,
    const float* __restrict__ W2, const float* __restrict__ b2,
    float* __restrict__ p_copy, float* __restrict__ lam) {
  extern __shared__ uint4 smem[];
  uint4* Bs = smem;          // 4096 chunks = 64 KB
  uint4* Ub = smem + 4096;   // 1024 chunks = 16 KB: row*64 + (slot ^ row)

  const int tid = threadIdx.x;
  const int lane = tid & 63;
  const int w = tid >> 6;    // 0..7
  const int lm = lane & 15;
  const int lg = lane >> 4;
  const int b = blockIdx.x >> 6;
  const int t0 = (blockIdx.x & 63) * 16;

  // ---- phase 0: prefetch lane's ex A-data (row m = w*16+lm) ----
  const int t_local = w * 2 + (lm >> 3);
  const int t = t0 + t_local;
  const int ctv = c_t[b * NT + t];
  const bool valid = ctv >= 0;
  const int c = valid ? ctv : 0;
  const float* arow = &ex[(((size_t)b * NK + (lm & 7)) * NL + c) * NE];
  float4 pf[8];
#pragma unroll
  for (int ks = 0; ks < 4; ++ks) {
    const int g = ks * 4 + lg;
    pf[2 * ks] = *(const float4*)(arow + g * 8);
    pf[2 * ks + 1] = *(const float4*)(arow + g * 8 + 4);
  }

  // ---- phase 1: async B stage (64 KB linear) ----
#pragma unroll
  for (int it = 0; it < 8; ++it) {
    const int off = (w * 8 + it) * 64;
    __builtin_amdgcn_global_load_lds(
        (const __attribute__((address_space(1))) void*)(imgEx + off + lane),
        (__attribute__((address_space(3))) void*)(Bs + off), 16, 0, 0);
  }

  // ---- phase 2: base part, M=16, batched global loads -> swizzled Ub ----
  {
    const int myt = t0 + lm;
    const int ctv2 = c_t[b * NT + myt];
    const int myc = ctv2 < 0 ? 0 : ctv2;
    f32x4 accB[2];
#pragma unroll
    for (int f = 0; f < 2; ++f) {
      const float4 bv = *(const float4*)&b1[(w * 2 + f) * 16 + lg * 4];
      accB[f][0] = bv.x; accB[f][1] = bv.y; accB[f][2] = bv.z; accB[f][3] = bv.w;
    }
#pragma unroll
    for (int hb = 0; hb < 2; ++hb) {
      // batch-issue 5 A-chunk loads + 10 B-chunk loads, then 10 MFMAs
      float4 f0a[5], f1a[5];
      uint4 bb[10];
#pragma unroll
      for (int i = 0; i < 5; ++i) {
        const int gk = (hb * 5 + i) * 4 + lg;  // 0..39
        const float* asrc = (gk < 32)
            ? &hs[((size_t)b * NT + myt) * NH + gk * 8]
            : &col[((size_t)b * NL + myc) * NF + (gk - 32) * 8];
        f0a[i] = *(const float4*)asrc;
        f1a[i] = *(const float4*)(asrc + 4);
      }
#pragma unroll
      for (int i = 0; i < 5; ++i) {
        const int gk = (hb * 5 + i) * 4 + lg;
#pragma unroll
        for (int f = 0; f < 2; ++f) {
          const int n = (w * 2 + f) * 16 + lm;
          bb[i * 2 + f] = imgB[(size_t)gk * 256 + (n ^ (gk & 7))];
        }
      }
#pragma unroll
      for (int i = 0; i < 5; ++i) {
        union { uint4 u; bf16x8 v; } A;
        A.u = pack8(f0a[i], f1a[i]);
#pragma unroll
        for (int f = 0; f < 2; ++f) {
          union { uint4 u; bf16x8 v; } B2;
          B2.u = bb[i * 2 + f];
          accB[f] = __builtin_amdgcn_mfma_f32_16x16x32_bf16(B2.v, A.v, accB[f], 0, 0, 0);
        }
      }
    }
    // deposit: row lm, 16B-slot s = (w*2+f)*4 + lg, phys = s ^ lm
#pragma unroll
    for (int f = 0; f < 2; ++f) {
      union { uint4 u; f32x4 v; } o;
      o.v = accB[f];
      Ub[lm * 64 + (((w * 2 + f) * 4 + lg) ^ lm)] = o.u;
    }
  }

  __syncthreads();

  // ---- phase 3: ex MFMA from prefetched regs + LDS B ----
  f32x4 acc[16] = {};
#pragma unroll
  for (int ks = 0; ks < 4; ++ks) {
    const int g = ks * 4 + lg;
    union { uint4 u; bf16x8 v; } A;
    A.u = pack8(pf[2 * ks], pf[2 * ks + 1]);
#pragma unroll
    for (int fn = 0; fn < 16; ++fn) {
      const bf16x8 bfr = *(const bf16x8*)&Bs[g * 256 + ((fn * 16 + lm) ^ (g & 7))];
      acc[fn] = __builtin_amdgcn_mfma_f32_16x16x32_bf16(bfr, A.v, acc[fn], 0, 0, 0);
    }
  }

  // ---- phase 4: epilogue ----
  const float b2v = b2[0];
  float p = 0.f;
#pragma unroll
  for (int fn = 0; fn < 16; ++fn) {
    const int n0 = fn * 16 + lg * 4;
    union { uint4 u; f32x4 v; } ubv;
    ubv.u = Ub[t_local * 64 + ((fn * 4 + lg) ^ t_local)];
    const float4 w2v = *(const float4*)&W2[n0];
    p += fmaxf(acc[fn][0] + ubv.v[0], 0.f) * w2v.x +
         fmaxf(acc[fn][1] + ubv.v[1], 0.f) * w2v.y +
         fmaxf(acc[fn][2] + ubv.v[2], 0.f) * w2v.z +
         fmaxf(acc[fn][3] + ubv.v[3], 0.f) * w2v.w;
  }
  p += __shfl_xor(p, 16);
  p += __shfl_xor(p, 32);
  const float score = p + b2v;

  float mx = score;
  mx = fmaxf(mx, __shfl_xor(mx, 1));
  mx = fmaxf(mx, __shfl_xor(mx, 2));
  mx = fmaxf(mx, __shfl_xor(mx, 4));
  const float e = __expf(score - mx);
  float s = e;
  s += __shfl_xor(s, 1);
  s += __shfl_xor(s, 2);
  s += __shfl_xor(s, 4);
  const float wgt = valid ? (e / s) : 0.f;

  // lambda: lg==0 lanes cover 2 t rows x 8 k = 16 consecutive floats
  if (lg == 0) lam[((size_t)b * NT + t0 + w * 2) * NK + lm] = wgt;

  int aav = 0;
  if (lg == 0) aav = aa_ids[((size_t)b * NK + (lm & 7)) * NL + c];

  const int bin = lane & 31;
  const int half = lane >> 5;
  const int src0 = half * 8;
  float pc = 0.f;
#pragma unroll
  for (int k = 0; k < 8; ++k) {
    const int a = __shfl(aav, src0 + k);
    const float ww = __shfl(wgt, src0 + k);
    pc += (a == bin) ? ww : 0.f;
  }
  if (bin < NV)
    p_copy[((size_t)b * NT + t0 + w * 2 + half) * NV + bin] = pc;
}

extern "C" void kernel_launch(void* const* d_in, const int* in_sizes, int n_in,
                              void* d_out, int out_size, void* d_ws, size_t ws_size,
                              hipStream_t stream) {
  const float* hs = (const float*)d_in[0];
  const float* ex = (const float*)d_in[1];
  const float* col = (const float*)d_in[2];
  const int* ct = (const int*)d_in[3];
  const int* aa = (const int*)d_in[4];
  const float* W1 = (const float*)d_in[5];
  const float* b1 = (const float*)d_in[6];
  const float* W2 = (const float*)d_in[7];
  const float* b2 = (const float*)d_in[8];

  uint4* imgEx = (uint4*)d_ws;        // 64 KB
  uint4* imgB = imgEx + 4096;         // 160 KB

  float* p_copy = (float*)d_out;
  float* lam = p_copy + (size_t)NB * NT * NV;

  const size_t lds_bytes = (4096 + 1024) * sizeof(uint4);  // 80 KB

  k_prep<<<56, 64, 0, stream>>>(W1, imgEx, imgB);
  k_mega<<<NB * NT / 16, 512, lds_bytes, stream>>>(hs, ex, col, ct, aa, imgEx,
                                                   imgB, b1, W2, b2, p_copy, lam);
}